// Round 16
// baseline (114.889 us; speedup 1.0000x reference)
//
#include <hip/hip_runtime.h>
#include <hip/hip_bf16.h>

// cos(2*pi*t/8), t = 0..7
__device__ const float C8[8] = {
    1.0f, 0.70710678118654752f, 0.0f, -0.70710678118654752f,
   -1.0f, -0.70710678118654752f, 0.0f, 0.70710678118654752f
};

// Unique-id map for the 8x8 circular-conv kernel (even in dy,dx + swap symm).
__host__ __device__ constexpr int kid(int dy, int dx) {
    int a = (dy < 8 - dy) ? dy : 8 - dy;
    int b = (dx < 8 - dx) ? dx : 8 - dx;
    int lo = a < b ? a : b, hi = a < b ? b : a;
    return lo * 5 - lo * (lo - 1) / 2 + (hi - lo);
}

// ---------------- channel mean: x(4,32,512,512) -> xm(4,512,512) ----------------
// Block 0 also zeroes the per-batch completion counters used by k_edgecoeff
// (re-zeroed every call -> deterministic across graph replays).
__global__ __launch_bounds__(256) void k_mean(const float* __restrict__ x,
                                              float* __restrict__ xm,
                                              int* __restrict__ cnt) {
    if (blockIdx.x == 0 && threadIdx.x < 4) cnt[threadIdx.x] = 0;
    int idx = blockIdx.x * 256 + threadIdx.x;   // float4 index, 262144 total
    int b = idx >> 16;
    int rem = idx & 65535;
    const float4* xp = (const float4*)x + (size_t)b * 32 * 65536 + rem;
    float4 acc = {0.f, 0.f, 0.f, 0.f};
    #pragma unroll 8
    for (int c = 0; c < 32; ++c) {
        float4 v = xp[(size_t)c * 65536];
        acc.x += v.x; acc.y += v.y; acc.z += v.z; acc.w += v.w;
    }
    const float s = 1.0f / 32.0f;
    acc.x *= s; acc.y *= s; acc.z *= s; acc.w *= s;
    ((float4*)xm)[idx] = acc;
}

// ---------------- fused: edge strength + (last block per batch) normalize ----------------
// grid 512 = b(4) x hti(64) x half(2); 128 blocks per batch. Each block
// computes es for its 32 patches; block 0 additionally builds K0|K1 from
// gain. The LAST finishing block of each batch (device-scope atomic
// counter) reduces that batch's es -> f. Saves one kernel launch + gap
// (round-15 post-mortem: k_main closed at mixed-stream rate; tail is the
// remaining budget).
__global__ __launch_bounds__(256) void k_edgecoeff(const float* __restrict__ xm,
                                                   float* __restrict__ es,
                                                   float* __restrict__ f,
                                                   const float* __restrict__ gain,
                                                   float* __restrict__ Kg,
                                                   int* __restrict__ cnt) {
    int blk = blockIdx.x;
    int half = blk & 1;
    int hti = (blk >> 1) & 63;
    int b = blk >> 7;
    int t = threadIdx.x;

    // ---- block 0: K0/K1 prep (independent of es; done before k_main runs) ----
    if (blk == 0) {
        __shared__ float m0[40], m1[40];
        if (t < 40) {
            int ky = t / 5, kx = t % 5;
            int kyp = (ky < 8 - ky) ? ky : (8 - ky);
            float r = sqrtf((float)(kyp * kyp + kx * kx)) / (sqrtf(32.0f) + 1e-8f);
            r = fminf(fmaxf(r, 0.0f), 1.0f);
            float wv[6], wsum = 0.0f;
            #pragma unroll
            for (int i = 0; i < 6; ++i) {
                float c = 0.2f * (float)i;
                float v = fmaxf(1.0f - fabsf(r - c) * 5.0f, 0.0f);
                wv[i] = v; wsum += v;
            }
            float inv = 1.0f / (wsum + 1e-8f);
            float acc = 0.0f;
            #pragma unroll
            for (int i = 0; i < 6; ++i) acc += wv[i] * inv * gain[i];
            float mask = fmaxf(acc, 0.0f);
            m0[t] = mask;
            m1[t] = (r >= 0.6f) ? mask : 0.0f;
        }
        __syncthreads();
        if (t < 64) {
            int a = t >> 3, bb = t & 7;
            float s0 = 0.0f, s1 = 0.0f;
            for (int ky = 0; ky < 8; ++ky) {
                for (int kx = 0; kx < 8; ++kx) {
                    int kxh = (kx <= 4) ? kx : (8 - kx);
                    float c = C8[(ky * a + kx * bb) & 7];
                    s0 += m0[ky * 5 + kxh] * c;
                    s1 += m1[ky * 5 + kxh] * c;
                }
            }
            Kg[t] = s0 * (1.0f / 64.0f);
            Kg[64 + t] = s1 * (1.0f / 64.0f);
        }
        __syncthreads();
    }

    // ---- edge phase: 32 patches (half-row) ----
    int w32 = t & 31;
    int q = t >> 5;
    int wt = half * 32 + w32;
    const float* base = xm + (size_t)b * 512 * 512;
    int y = hti * 8 + q;
    float partial = 0.0f;
    for (int x0 = 0; x0 < 8; ++x0) {
        int xx = wt * 8 + x0;
        float n[3][3];
        #pragma unroll
        for (int dy = -1; dy <= 1; ++dy) {
            #pragma unroll
            for (int dx = -1; dx <= 1; ++dx) {
                int yy = y + dy, xc = xx + dx;
                float v = 0.0f;
                if (yy >= 0 && yy < 512 && xc >= 0 && xc < 512)
                    v = base[yy * 512 + xc];
                n[dy + 1][dx + 1] = v;
            }
        }
        float gx = (n[0][2] - n[0][0]) + 2.0f * (n[1][2] - n[1][0]) + (n[2][2] - n[2][0]);
        float gy = (n[2][0] - n[0][0]) + 2.0f * (n[2][1] - n[0][1]) + (n[2][2] - n[0][2]);
        partial += sqrtf(gx * gx + gy * gy + 1e-6f);
    }
    __shared__ float sred[256];
    sred[t] = partial;
    __syncthreads();
    if (t < 32) {
        float s = 0.0f;
        #pragma unroll
        for (int qq = 0; qq < 8; ++qq) s += sred[qq * 32 + t];
        es[((size_t)b * 64 + hti) * 64 + half * 32 + t] = s * (1.0f / 64.0f);
    }

    // ---- last block of this batch: es -> f ----
    __shared__ int isLast;
    __threadfence();                      // make our es writes visible first
    __syncthreads();
    if (t == 0) {
        int old = atomicAdd(&cnt[b], 1);
        isLast = (old == 127) ? 1 : 0;
    }
    __syncthreads();
    if (!isLast) return;
    __threadfence();                      // order: see all blocks' es writes

    const float* e = es + (size_t)b * 4096;
    float mn = 1e30f, mx = -1e30f;
    for (int i = t; i < 4096; i += 256) {
        float v = e[i];
        mn = fminf(mn, v); mx = fmaxf(mx, v);
    }
    #pragma unroll
    for (int off = 32; off > 0; off >>= 1) {
        mn = fminf(mn, __shfl_down(mn, off));
        mx = fmaxf(mx, __shfl_down(mx, off));
    }
    __shared__ float smn[4], smx[4];
    if ((t & 63) == 0) { smn[t >> 6] = mn; smx[t >> 6] = mx; }
    __syncthreads();
    mn = fminf(fminf(smn[0], smn[1]), fminf(smn[2], smn[3]));
    mx = fmaxf(fmaxf(smx[0], smx[1]), fmaxf(smx[2], smx[3]));
    float scale = 0.5f / (mx - mn + 1e-6f);
    for (int i = t; i < 4096; i += 256) {
        f[(size_t)b * 4096 + i] = (e[i] - mn) * scale;
    }
}

// conv2: add conv_x(V, krow KA) into a0 and conv_x(V, krow KB) into a1,
// x-even fold shared between both output rows. All indices compile-time.
template<int KA, int KB>
__device__ __forceinline__ void conv2(const float (&V)[8], const float (&k)[15],
                                      float (&a0)[8], float (&a1)[8]) {
    float t1[8], t2[8], t3[8];
    #pragma unroll
    for (int x = 0; x < 8; ++x) {
        t1[x] = V[(x + 1) & 7] + V[(x + 7) & 7];
        t2[x] = V[(x + 2) & 7] + V[(x + 6) & 7];
        t3[x] = V[(x + 3) & 7] + V[(x + 5) & 7];
    }
    #pragma unroll
    for (int x = 0; x < 8; ++x) {
        a0[x] = fmaf(k[kid(KA, 0)], V[x], a0[x]);
        a0[x] = fmaf(k[kid(KA, 4)], V[(x + 4) & 7], a0[x]);
        a0[x] = fmaf(k[kid(KA, 1)], t1[x], a0[x]);
        a0[x] = fmaf(k[kid(KA, 2)], t2[x], a0[x]);
        a0[x] = fmaf(k[kid(KA, 3)], t3[x], a0[x]);
        a1[x] = fmaf(k[kid(KB, 0)], V[x], a1[x]);
        a1[x] = fmaf(k[kid(KB, 4)], V[(x + 4) & 7], a1[x]);
        a1[x] = fmaf(k[kid(KB, 1)], t1[x], a1[x]);
        a1[x] = fmaf(k[kid(KB, 2)], t2[x], a1[x]);
        a1[x] = fmaf(k[kid(KB, 3)], t3[x], a1[x]);
    }
}

__device__ __forceinline__ void loadrow(const float* __restrict__ row, float (&V)[8]) {
    float4 p0 = *(const float4*)(row);
    float4 p1 = *(const float4*)(row + 4);
    V[0] = p0.x; V[1] = p0.y; V[2] = p0.z; V[3] = p0.w;
    V[4] = p1.x; V[5] = p1.y; V[6] = p1.z; V[7] = p1.w;
}

// Dense-store epilogue (R13, confirmed -13us): one wave owns an output row
// of all 64 patches (512 contiguous floats); shuffle so lane l stores the
// float4 at 4l (from lane l>>1) and 256+4l (from lane 32+(l>>1)) -> two
// 1KB lane-dense store instructions, 16 full lines each.
__device__ __forceinline__ void dense_store(float* __restrict__ rowp,
                                            const float (&acc)[8], int l) {
    const int e = l & 1;
    const int s0 = l >> 1;
    const int s1 = 32 + (l >> 1);
    float sa[4], sb[4];
    #pragma unroll
    for (int cmp = 0; cmp < 4; ++cmp) {
        float a0 = __shfl(acc[cmp], s0);
        float a1 = __shfl(acc[cmp + 4], s0);
        sa[cmp] = e ? a1 : a0;
        float b0 = __shfl(acc[cmp], s1);
        float b1 = __shfl(acc[cmp + 4], s1);
        sb[cmp] = e ? b1 : b0;
    }
    float4 vA = {sa[0], sa[1], sa[2], sa[3]};
    float4 vB = {sb[0], sb[1], sb[2], sb[3]};
    *(float4*)(rowp + l * 4) = vA;
    *(float4*)(rowp + 256 + l * 4) = vB;
}

// ---------------- main: per-patch circular conv with K_eff = K0 + f*K1 ----------------
// R13 structure verbatim (best measured: strided reads, dense shuffled
// plain stores). Closed at the mixed-stream memory rate (~3.8 TB/s): nine
// variants (ops -47%, 2x occupancy, dense/fp16/LDS reads, NT stores) all
// land 52 +/- 2 us.
__global__ __launch_bounds__(256) void k_main(const float* __restrict__ x,
                                              const float* __restrict__ Kg,
                                              const float* __restrict__ f,
                                              float* __restrict__ out) {
    // grid: 8192 = b(4) * c(32) * hti(64); block 256: q(4, wave) x w(64, lane)
    int blk = blockIdx.x;
    int hti = blk & 63;
    int c = (blk >> 6) & 31;
    int b = blk >> 11;
    int t = threadIdx.x;
    int w = t & 63;
    int q = t >> 6;             // wave id: output rows q and q+4

    float fc = f[((size_t)b * 64 + hti) * 64 + w];

    size_t pbase = (((size_t)(b * 32 + c) * 512) + (size_t)hti * 8) * 512;
    const float* src = x + pbase + w * 8;

    float k[15];
    #pragma unroll
    for (int a = 0; a <= 4; ++a) {
        #pragma unroll
        for (int d = a; d <= 4; ++d) {
            k[kid(a, d)] = fmaf(fc, Kg[64 + a * 8 + d], Kg[a * 8 + d]);
        }
    }

    float acc0[8], acc1[8];
    #pragma unroll
    for (int i = 0; i < 8; ++i) { acc0[i] = 0.0f; acc1[i] = 0.0f; }

    // singles: row q (krow0 -> out0, krow4 -> out1), row q+4 (krow4/krow0)
    {
        float V[8];
        loadrow(src + (size_t)q * 512, V);
        conv2<0, 4>(V, k, acc0, acc1);
    }
    {
        float V[8];
        loadrow(src + (size_t)(q + 4) * 512, V);
        conv2<4, 0>(V, k, acc0, acc1);
    }
    // pairs R_d = p(q+d) + p(q-d): out0 uses krow d, out1 uses krow 4-d
    {
        float A[8], B[8], V[8];
        loadrow(src + (size_t)((q + 1) & 7) * 512, A);
        loadrow(src + (size_t)((q + 7) & 7) * 512, B);
        #pragma unroll
        for (int i = 0; i < 8; ++i) V[i] = A[i] + B[i];
        conv2<1, 3>(V, k, acc0, acc1);
    }
    {
        float A[8], B[8], V[8];
        loadrow(src + (size_t)((q + 2) & 7) * 512, A);
        loadrow(src + (size_t)((q + 6) & 7) * 512, B);
        #pragma unroll
        for (int i = 0; i < 8; ++i) V[i] = A[i] + B[i];
        conv2<2, 2>(V, k, acc0, acc1);
    }
    {
        float A[8], B[8], V[8];
        loadrow(src + (size_t)((q + 3) & 7) * 512, A);
        loadrow(src + (size_t)((q + 5) & 7) * 512, B);
        #pragma unroll
        for (int i = 0; i < 8; ++i) V[i] = A[i] + B[i];
        conv2<3, 1>(V, k, acc0, acc1);
    }

    // dense stores: wave q writes rows q and q+4 of all 64 patches
    dense_store(out + pbase + (size_t)q * 512, acc0, w);
    dense_store(out + pbase + (size_t)(q + 4) * 512, acc1, w);
}

extern "C" void kernel_launch(void* const* d_in, const int* in_sizes, int n_in,
                              void* d_out, int out_size, void* d_ws, size_t ws_size,
                              hipStream_t stream) {
    const float* x    = (const float*)d_in[0];   // (4,32,512,512)
    const float* gain = (const float*)d_in[1];   // (1,6)
    float* out = (float*)d_out;
    float* ws = (float*)d_ws;

    float* Kg = ws;                      // 128 floats: K0 | K1
    float* f  = ws + 128;                // 4*4096
    float* es = ws + 128 + 16384;        // 4*4096
    float* xm = ws + 128 + 2 * 16384;    // 4*512*512
    int*   cnt = (int*)(ws + 128 + 2 * 16384 + 1048576);  // 4 ints

    hipLaunchKernelGGL(k_mean, dim3(1024), dim3(256), 0, stream, x, xm, cnt);
    hipLaunchKernelGGL(k_edgecoeff, dim3(512), dim3(256), 0, stream,
                       xm, es, f, gain, Kg, cnt);
    hipLaunchKernelGGL(k_main, dim3(8192), dim3(256), 0, stream, x, Kg, f, out);
}

// Round 17
// 88.646 us; speedup vs baseline: 1.2960x; 1.2960x over previous
//
#include <hip/hip_runtime.h>
#include <hip/hip_bf16.h>

// cos(2*pi*t/8), t = 0..7
__device__ const float C8[8] = {
    1.0f, 0.70710678118654752f, 0.0f, -0.70710678118654752f,
   -1.0f, -0.70710678118654752f, 0.0f, 0.70710678118654752f
};

// Unique-id map for the 8x8 circular-conv kernel (even in dy,dx + swap symm).
__host__ __device__ constexpr int kid(int dy, int dx) {
    int a = (dy < 8 - dy) ? dy : 8 - dy;
    int b = (dx < 8 - dx) ? dx : 8 - dx;
    int lo = a < b ? a : b, hi = a < b ? b : a;
    return lo * 5 - lo * (lo - 1) / 2 + (hi - lo);
}

// ---------------- channel mean: x(4,32,512,512) -> xm(4,512,512) ----------------
__global__ __launch_bounds__(256) void k_mean(const float* __restrict__ x,
                                              float* __restrict__ xm) {
    int idx = blockIdx.x * 256 + threadIdx.x;   // float4 index, 262144 total
    int b = idx >> 16;
    int rem = idx & 65535;
    const float4* xp = (const float4*)x + (size_t)b * 32 * 65536 + rem;
    float4 acc = {0.f, 0.f, 0.f, 0.f};
    #pragma unroll 8
    for (int c = 0; c < 32; ++c) {
        float4 v = xp[(size_t)c * 65536];
        acc.x += v.x; acc.y += v.y; acc.z += v.z; acc.w += v.w;
    }
    const float s = 1.0f / 32.0f;
    acc.x *= s; acc.y *= s; acc.z *= s; acc.w *= s;
    ((float4*)xm)[idx] = acc;
}

// ---------------- edge strength per patch: xm -> es(4,64,64) ----------------
__global__ __launch_bounds__(256) void k_edge(const float* __restrict__ xm,
                                              float* __restrict__ es) {
    int blk = blockIdx.x;
    int half = blk & 1;
    int hti = (blk >> 1) & 63;
    int b = blk >> 7;
    int t = threadIdx.x;
    int w32 = t & 31;
    int q = t >> 5;
    int wt = half * 32 + w32;
    const float* base = xm + (size_t)b * 512 * 512;
    int y = hti * 8 + q;
    float partial = 0.0f;
    for (int x0 = 0; x0 < 8; ++x0) {
        int xx = wt * 8 + x0;
        float n[3][3];
        #pragma unroll
        for (int dy = -1; dy <= 1; ++dy) {
            #pragma unroll
            for (int dx = -1; dx <= 1; ++dx) {
                int yy = y + dy, xc = xx + dx;
                float v = 0.0f;
                if (yy >= 0 && yy < 512 && xc >= 0 && xc < 512)
                    v = base[yy * 512 + xc];
                n[dy + 1][dx + 1] = v;
            }
        }
        float gx = (n[0][2] - n[0][0]) + 2.0f * (n[1][2] - n[1][0]) + (n[2][2] - n[2][0]);
        float gy = (n[2][0] - n[0][0]) + 2.0f * (n[2][1] - n[0][1]) + (n[2][2] - n[0][2]);
        partial += sqrtf(gx * gx + gy * gy + 1e-6f);
    }
    __shared__ float sred[256];
    sred[t] = partial;
    __syncthreads();
    if (t < 32) {
        float s = 0.0f;
        #pragma unroll
        for (int qq = 0; qq < 8; ++qq) s += sred[qq * 32 + t];
        es[((size_t)b * 64 + hti) * 64 + half * 32 + t] = s * (1.0f / 64.0f);
    }
}

// ---------------- per-batch normalize + (block 4) K0/K1 prep ----------------
__global__ __launch_bounds__(256) void k_coeff_prep(const float* __restrict__ es,
                                                    float* __restrict__ f,
                                                    const float* __restrict__ gain,
                                                    float* __restrict__ Kg) {
    int b = blockIdx.x;
    int t = threadIdx.x;
    if (b == 4) {
        __shared__ float m0[40], m1[40];
        if (t < 40) {
            int ky = t / 5, kx = t % 5;
            int kyp = (ky < 8 - ky) ? ky : (8 - ky);
            float r = sqrtf((float)(kyp * kyp + kx * kx)) / (sqrtf(32.0f) + 1e-8f);
            r = fminf(fmaxf(r, 0.0f), 1.0f);
            float wv[6], wsum = 0.0f;
            #pragma unroll
            for (int i = 0; i < 6; ++i) {
                float c = 0.2f * (float)i;
                float v = fmaxf(1.0f - fabsf(r - c) * 5.0f, 0.0f);
                wv[i] = v; wsum += v;
            }
            float inv = 1.0f / (wsum + 1e-8f);
            float acc = 0.0f;
            #pragma unroll
            for (int i = 0; i < 6; ++i) acc += wv[i] * inv * gain[i];
            float mask = fmaxf(acc, 0.0f);
            m0[t] = mask;
            m1[t] = (r >= 0.6f) ? mask : 0.0f;
        }
        __syncthreads();
        if (t < 64) {
            int a = t >> 3, bb = t & 7;
            float s0 = 0.0f, s1 = 0.0f;
            for (int ky = 0; ky < 8; ++ky) {
                for (int kx = 0; kx < 8; ++kx) {
                    int kxh = (kx <= 4) ? kx : (8 - kx);
                    float c = C8[(ky * a + kx * bb) & 7];
                    s0 += m0[ky * 5 + kxh] * c;
                    s1 += m1[ky * 5 + kxh] * c;
                }
            }
            Kg[t] = s0 * (1.0f / 64.0f);
            Kg[64 + t] = s1 * (1.0f / 64.0f);
        }
        return;
    }
    const float* e = es + (size_t)b * 4096;
    float mn = 1e30f, mx = -1e30f;
    for (int i = t; i < 4096; i += 256) {
        float v = e[i];
        mn = fminf(mn, v); mx = fmaxf(mx, v);
    }
    #pragma unroll
    for (int off = 32; off > 0; off >>= 1) {
        mn = fminf(mn, __shfl_down(mn, off));
        mx = fmaxf(mx, __shfl_down(mx, off));
    }
    __shared__ float smn[4], smx[4];
    if ((t & 63) == 0) { smn[t >> 6] = mn; smx[t >> 6] = mx; }
    __syncthreads();
    mn = fminf(fminf(smn[0], smn[1]), fminf(smn[2], smn[3]));
    mx = fmaxf(fmaxf(smx[0], smx[1]), fmaxf(smx[2], smx[3]));
    float scale = 0.5f / (mx - mn + 1e-6f);
    for (int i = t; i < 4096; i += 256) {
        f[(size_t)b * 4096 + i] = (e[i] - mn) * scale;
    }
}

// conv2: add conv_x(V, krow KA) into a0 and conv_x(V, krow KB) into a1,
// x-even fold shared between both output rows. All indices compile-time.
template<int KA, int KB>
__device__ __forceinline__ void conv2(const float (&V)[8], const float (&k)[15],
                                      float (&a0)[8], float (&a1)[8]) {
    float t1[8], t2[8], t3[8];
    #pragma unroll
    for (int x = 0; x < 8; ++x) {
        t1[x] = V[(x + 1) & 7] + V[(x + 7) & 7];
        t2[x] = V[(x + 2) & 7] + V[(x + 6) & 7];
        t3[x] = V[(x + 3) & 7] + V[(x + 5) & 7];
    }
    #pragma unroll
    for (int x = 0; x < 8; ++x) {
        a0[x] = fmaf(k[kid(KA, 0)], V[x], a0[x]);
        a0[x] = fmaf(k[kid(KA, 4)], V[(x + 4) & 7], a0[x]);
        a0[x] = fmaf(k[kid(KA, 1)], t1[x], a0[x]);
        a0[x] = fmaf(k[kid(KA, 2)], t2[x], a0[x]);
        a0[x] = fmaf(k[kid(KA, 3)], t3[x], a0[x]);
        a1[x] = fmaf(k[kid(KB, 0)], V[x], a1[x]);
        a1[x] = fmaf(k[kid(KB, 4)], V[(x + 4) & 7], a1[x]);
        a1[x] = fmaf(k[kid(KB, 1)], t1[x], a1[x]);
        a1[x] = fmaf(k[kid(KB, 2)], t2[x], a1[x]);
        a1[x] = fmaf(k[kid(KB, 3)], t3[x], a1[x]);
    }
}

__device__ __forceinline__ void loadrow(const float* __restrict__ row, float (&V)[8]) {
    float4 p0 = *(const float4*)(row);
    float4 p1 = *(const float4*)(row + 4);
    V[0] = p0.x; V[1] = p0.y; V[2] = p0.z; V[3] = p0.w;
    V[4] = p1.x; V[5] = p1.y; V[6] = p1.z; V[7] = p1.w;
}

// Dense-store epilogue (R13, confirmed -13us): one wave owns an output row
// of all 64 patches (512 contiguous floats); shuffle so lane l stores the
// float4 at 4l (from lane l>>1) and 256+4l (from lane 32+(l>>1)) -> two
// 1KB lane-dense store instructions, 16 full lines each.
__device__ __forceinline__ void dense_store(float* __restrict__ rowp,
                                            const float (&acc)[8], int l) {
    const int e = l & 1;
    const int s0 = l >> 1;
    const int s1 = 32 + (l >> 1);
    float sa[4], sb[4];
    #pragma unroll
    for (int cmp = 0; cmp < 4; ++cmp) {
        float a0 = __shfl(acc[cmp], s0);
        float a1 = __shfl(acc[cmp + 4], s0);
        sa[cmp] = e ? a1 : a0;
        float b0 = __shfl(acc[cmp], s1);
        float b1 = __shfl(acc[cmp + 4], s1);
        sb[cmp] = e ? b1 : b0;
    }
    float4 vA = {sa[0], sa[1], sa[2], sa[3]};
    float4 vB = {sb[0], sb[1], sb[2], sb[3]};
    *(float4*)(rowp + l * 4) = vA;
    *(float4*)(rowp + 256 + l * 4) = vB;
}

// ---------------- main: per-patch circular conv with K_eff = K0 + f*K1 ----------------
// R13 structure verbatim (best measured, 88.96 us total): strided reads,
// dense shuffled plain stores. Closed at the mixed-stream memory rate
// (~3.8 TB/s): nine variants (ops -47%, 2x occupancy, dense/fp16/LDS
// reads, NT stores) all land 52 +/- 2 us.
__global__ __launch_bounds__(256) void k_main(const float* __restrict__ x,
                                              const float* __restrict__ Kg,
                                              const float* __restrict__ f,
                                              float* __restrict__ out) {
    // grid: 8192 = b(4) * c(32) * hti(64); block 256: q(4, wave) x w(64, lane)
    int blk = blockIdx.x;
    int hti = blk & 63;
    int c = (blk >> 6) & 31;
    int b = blk >> 11;
    int t = threadIdx.x;
    int w = t & 63;
    int q = t >> 6;             // wave id: output rows q and q+4

    float fc = f[((size_t)b * 64 + hti) * 64 + w];

    size_t pbase = (((size_t)(b * 32 + c) * 512) + (size_t)hti * 8) * 512;
    const float* src = x + pbase + w * 8;

    float k[15];
    #pragma unroll
    for (int a = 0; a <= 4; ++a) {
        #pragma unroll
        for (int d = a; d <= 4; ++d) {
            k[kid(a, d)] = fmaf(fc, Kg[64 + a * 8 + d], Kg[a * 8 + d]);
        }
    }

    float acc0[8], acc1[8];
    #pragma unroll
    for (int i = 0; i < 8; ++i) { acc0[i] = 0.0f; acc1[i] = 0.0f; }

    // singles: row q (krow0 -> out0, krow4 -> out1), row q+4 (krow4/krow0)
    {
        float V[8];
        loadrow(src + (size_t)q * 512, V);
        conv2<0, 4>(V, k, acc0, acc1);
    }
    {
        float V[8];
        loadrow(src + (size_t)(q + 4) * 512, V);
        conv2<4, 0>(V, k, acc0, acc1);
    }
    // pairs R_d = p(q+d) + p(q-d): out0 uses krow d, out1 uses krow 4-d
    {
        float A[8], B[8], V[8];
        loadrow(src + (size_t)((q + 1) & 7) * 512, A);
        loadrow(src + (size_t)((q + 7) & 7) * 512, B);
        #pragma unroll
        for (int i = 0; i < 8; ++i) V[i] = A[i] + B[i];
        conv2<1, 3>(V, k, acc0, acc1);
    }
    {
        float A[8], B[8], V[8];
        loadrow(src + (size_t)((q + 2) & 7) * 512, A);
        loadrow(src + (size_t)((q + 6) & 7) * 512, B);
        #pragma unroll
        for (int i = 0; i < 8; ++i) V[i] = A[i] + B[i];
        conv2<2, 2>(V, k, acc0, acc1);
    }
    {
        float A[8], B[8], V[8];
        loadrow(src + (size_t)((q + 3) & 7) * 512, A);
        loadrow(src + (size_t)((q + 5) & 7) * 512, B);
        #pragma unroll
        for (int i = 0; i < 8; ++i) V[i] = A[i] + B[i];
        conv2<3, 1>(V, k, acc0, acc1);
    }

    // dense stores: wave q writes rows q and q+4 of all 64 patches
    dense_store(out + pbase + (size_t)q * 512, acc0, w);
    dense_store(out + pbase + (size_t)(q + 4) * 512, acc1, w);
}

extern "C" void kernel_launch(void* const* d_in, const int* in_sizes, int n_in,
                              void* d_out, int out_size, void* d_ws, size_t ws_size,
                              hipStream_t stream) {
    const float* x    = (const float*)d_in[0];   // (4,32,512,512)
    const float* gain = (const float*)d_in[1];   // (1,6)
    float* out = (float*)d_out;
    float* ws = (float*)d_ws;

    float* Kg = ws;                      // 128 floats: K0 | K1
    float* f  = ws + 128;                // 4*4096
    float* es = ws + 128 + 16384;        // 4*4096
    float* xm = ws + 128 + 2 * 16384;    // 4*512*512

    hipLaunchKernelGGL(k_mean, dim3(1024), dim3(256), 0, stream, x, xm);
    hipLaunchKernelGGL(k_edge, dim3(512), dim3(256), 0, stream, xm, es);
    hipLaunchKernelGGL(k_coeff_prep, dim3(5), dim3(256), 0, stream, es, f, gain, Kg);
    hipLaunchKernelGGL(k_main, dim3(8192), dim3(256), 0, stream, x, Kg, f, out);
}